// Round 1
// baseline (5783.776 us; speedup 1.0000x reference)
//
#include <hip/hip_runtime.h>

#define NNODES 100000
#define NEDGES 1600000

static constexpr float EPS = 1e-12f;

// order-preserving f32 <-> u32 encoding for atomicMax-based segment max
__device__ __forceinline__ unsigned enc_f32(float x) {
    unsigned b = __float_as_uint(x);
    return (b & 0x80000000u) ? ~b : (b | 0x80000000u);
}
__device__ __forceinline__ float dec_f32(unsigned u) {
    unsigned b = (u & 0x80000000u) ? (u ^ 0x80000000u) : ~u;
    return __uint_as_float(b);
}

// h[N,32] = relu(feat[N,128] @ w1[32,128]^T + b1)
__global__ __launch_bounds__(256) void k_lin1(
    const float* __restrict__ feat, const float* __restrict__ w1,
    const float* __restrict__ b1, float* __restrict__ h)
{
    __shared__ float w1s[32][129];   // +1 pad -> conflict-free column reads
    __shared__ float fs[8][128];
    for (int i = threadIdx.x; i < 32 * 128; i += 256)
        w1s[i >> 7][i & 127] = w1[i];
    int row0 = blockIdx.x * 8;
    for (int i = threadIdx.x; i < 8 * 128; i += 256) {
        int r = row0 + (i >> 7);
        fs[i >> 7][i & 127] = (r < NNODES) ? feat[r * 128 + (i & 127)] : 0.f;
    }
    __syncthreads();
    int r = threadIdx.x >> 5, c = threadIdx.x & 31;
    int row = row0 + r;
    if (row >= NNODES) return;
    float acc = b1[c];
    #pragma unroll
    for (int k = 0; k < 128; ++k) acc += fs[r][k] * w1s[c][k];
    h[row * 32 + c] = fmaxf(acc, 0.f);
}

// Per-row: optionally (h = relu(h / max(denom,eps)) written back), then
// rnorm = 1/max(||h||,eps)
__global__ __launch_bounds__(256) void k_norm(
    float* __restrict__ h, const float* __restrict__ denom,
    float* __restrict__ rnorm, int do_fix)
{
    int row = blockIdx.x * 256 + threadIdx.x;
    if (row >= NNODES) return;
    float4* hp = reinterpret_cast<float4*>(h + row * 32);
    float inv = 1.f;
    if (do_fix) inv = 1.f / fmaxf(denom[row], EPS);
    float ss = 0.f;
    #pragma unroll
    for (int i = 0; i < 8; ++i) {
        float4 t = hp[i];
        if (do_fix) {
            t.x = fmaxf(t.x * inv, 0.f);
            t.y = fmaxf(t.y * inv, 0.f);
            t.z = fmaxf(t.z * inv, 0.f);
            t.w = fmaxf(t.w * inv, 0.f);
            hp[i] = t;
        }
        ss += t.x * t.x + t.y * t.y + t.z * t.z + t.w * t.w;
    }
    rnorm[row] = 1.f / fmaxf(sqrtf(ss), EPS);
}

// e[k] = beta * rnorm[s] * rnorm[d] * dot(h[s], h[d]); segment-max into m_enc
__global__ __launch_bounds__(256) void k_edge_score(
    const float* __restrict__ h, const float* __restrict__ rnorm,
    const int* __restrict__ src, const int* __restrict__ dst,
    const float* __restrict__ betas, int layer,
    float* __restrict__ e, unsigned* __restrict__ m_enc)
{
    int k = blockIdx.x * 256 + threadIdx.x;
    if (k >= NEDGES) return;
    int s = src[k], d = dst[k];
    const float4* hs4 = reinterpret_cast<const float4*>(h + (size_t)s * 32);
    const float4* hd4 = reinterpret_cast<const float4*>(h + (size_t)d * 32);
    float acc = 0.f;
    #pragma unroll
    for (int i = 0; i < 8; ++i) {
        float4 a = hs4[i], b = hd4[i];
        acc += a.x * b.x + a.y * b.y + a.z * b.z + a.w * b.w;
    }
    float ev = betas[layer] * rnorm[s] * rnorm[d] * acc;
    e[k] = ev;
    atomicMax(m_enc + d, enc_f32(ev));
}

// ex = exp(e - m[dst]); denom[dst] += ex; hout[dst,:] += ex * h[src,:]
// (the alpha division is deferred to the consumer of hout)
__global__ __launch_bounds__(256) void k_edge_exp_scatter(
    const float* __restrict__ h, const int* __restrict__ src,
    const int* __restrict__ dst, const unsigned* __restrict__ m_enc,
    const float* __restrict__ e, float* __restrict__ denom,
    float* __restrict__ hout)
{
    int k = blockIdx.x * 256 + threadIdx.x;
    if (k >= NEDGES) return;
    int s = src[k], d = dst[k];
    unsigned u = m_enc[d];
    float m = (u == 0u) ? 0.f : dec_f32(u);
    float ex = expf(e[k] - m);
    atomicAdd(&denom[d], ex);
    const float4* hs4 = reinterpret_cast<const float4*>(h + (size_t)s * 32);
    float* o = hout + (size_t)d * 32;
    #pragma unroll
    for (int i = 0; i < 8; ++i) {
        float4 a = hs4[i];
        atomicAdd(o + 4 * i,     ex * a.x);
        atomicAdd(o + 4 * i + 1, ex * a.y);
        atomicAdd(o + 4 * i + 2, ex * a.z);
        atomicAdd(o + 4 * i + 3, ex * a.w);
    }
}

// out[N,64] = log_softmax(relu(h/denom) @ w2[64,32]^T + b2)
__global__ __launch_bounds__(256) void k_final(
    const float* __restrict__ h, const float* __restrict__ denom,
    const float* __restrict__ w2, const float* __restrict__ b2,
    float* __restrict__ out)
{
    __shared__ float w2s[64][33];    // +1 pad
    __shared__ float hs[4][32];
    for (int i = threadIdx.x; i < 64 * 32; i += 256)
        w2s[i >> 5][i & 31] = w2[i];
    int row0 = blockIdx.x * 4;
    if (threadIdx.x < 128) {
        int r = row0 + (threadIdx.x >> 5);
        int k = threadIdx.x & 31;
        float v = 0.f;
        if (r < NNODES)
            v = fmaxf(h[r * 32 + k] / fmaxf(denom[r], EPS), 0.f);
        hs[threadIdx.x >> 5][k] = v;
    }
    __syncthreads();
    int r = threadIdx.x >> 6, c = threadIdx.x & 63;
    int row = row0 + r;
    if (row >= NNODES) return;
    float acc = b2[c];
    #pragma unroll
    for (int k = 0; k < 32; ++k) acc += hs[r][k] * w2s[c][k];
    // one wave (64 lanes) == one row -> pure shuffle log-softmax
    float mx = acc;
    #pragma unroll
    for (int off = 32; off > 0; off >>= 1)
        mx = fmaxf(mx, __shfl_xor(mx, off));
    float ex = expf(acc - mx);
    float sm = ex;
    #pragma unroll
    for (int off = 32; off > 0; off >>= 1)
        sm += __shfl_xor(sm, off);
    out[row * 64 + c] = acc - mx - logf(sm);
}

extern "C" void kernel_launch(void* const* d_in, const int* in_sizes, int n_in,
                              void* d_out, int out_size, void* d_ws, size_t ws_size,
                              hipStream_t stream)
{
    const float* feat  = (const float*)d_in[0];
    const int*   src   = (const int*)d_in[1];
    const int*   dst   = (const int*)d_in[2];
    const float* w1    = (const float*)d_in[3];
    const float* b1    = (const float*)d_in[4];
    const float* betas = (const float*)d_in[5];
    const float* w2    = (const float*)d_in[6];
    const float* b2    = (const float*)d_in[7];
    float* out = (float*)d_out;

    // workspace layout (all f32): hA[N*32] hB[N*32] rnorm[N] m_enc[N]
    // denomA[N] denomB[N] e[E]  => ~33.6 MB
    float*    hA     = (float*)d_ws;
    float*    hB     = hA + (size_t)NNODES * 32;
    float*    rnorm  = hB + (size_t)NNODES * 32;
    unsigned* m_enc  = (unsigned*)(rnorm + NNODES);
    float*    denomA = (float*)(m_enc + NNODES);
    float*    denomB = denomA + NNODES;
    float*    ebuf   = denomB + NNODES;

    dim3 blk(256);
    int gLin  = (NNODES + 7) / 8;
    int gNode = (NNODES + 255) / 256;
    int gEdge = (NEDGES + 255) / 256;
    int gFin  = (NNODES + 3) / 4;

    k_lin1<<<gLin, blk, 0, stream>>>(feat, w1, b1, hA);

    // ---- AGNN layer 1: hA -> hB (un-divided), denomA
    hipMemsetAsync(m_enc,  0, (size_t)NNODES * 4, stream);
    hipMemsetAsync(denomA, 0, (size_t)NNODES * 4, stream);
    hipMemsetAsync(hB,     0, (size_t)NNODES * 32 * 4, stream);
    k_norm<<<gNode, blk, 0, stream>>>(hA, nullptr, rnorm, 0);
    k_edge_score<<<gEdge, blk, 0, stream>>>(hA, rnorm, src, dst, betas, 0, ebuf, m_enc);
    k_edge_exp_scatter<<<gEdge, blk, 0, stream>>>(hA, src, dst, m_enc, ebuf, denomA, hB);

    // ---- AGNN layer 2: hB (divide by denomA + relu in k_norm) -> hA, denomB
    hipMemsetAsync(m_enc,  0, (size_t)NNODES * 4, stream);
    hipMemsetAsync(denomB, 0, (size_t)NNODES * 4, stream);
    hipMemsetAsync(hA,     0, (size_t)NNODES * 32 * 4, stream);
    k_norm<<<gNode, blk, 0, stream>>>(hB, denomA, rnorm, 1);
    k_edge_score<<<gEdge, blk, 0, stream>>>(hB, rnorm, src, dst, betas, 1, ebuf, m_enc);
    k_edge_exp_scatter<<<gEdge, blk, 0, stream>>>(hB, src, dst, m_enc, ebuf, denomB, hA);

    // ---- final linear + log_softmax (divide hA by denomB + relu on load)
    k_final<<<gFin, blk, 0, stream>>>(hA, denomB, w2, b2, out);
}

// Round 2
// 694.362 us; speedup vs baseline: 8.3296x; 8.3296x over previous
//
#include <hip/hip_runtime.h>

#define NNODES 100000
#define NEDGES 1600000

static constexpr float EPS = 1e-12f;
static constexpr float NEG = -1e30f;   // finite "-inf": avoids NaN in empty-group merges

// h[N,32] = relu(feat[N,128] @ w1[32,128]^T + b1)
__global__ __launch_bounds__(256) void k_lin1(
    const float* __restrict__ feat, const float* __restrict__ w1,
    const float* __restrict__ b1, float* __restrict__ h)
{
    __shared__ float w1s[32][129];
    __shared__ float fs[8][128];
    for (int i = threadIdx.x; i < 32 * 128; i += 256)
        w1s[i >> 7][i & 127] = w1[i];
    int row0 = blockIdx.x * 8;
    for (int i = threadIdx.x; i < 8 * 128; i += 256) {
        int r = row0 + (i >> 7);
        fs[i >> 7][i & 127] = (r < NNODES) ? feat[r * 128 + (i & 127)] : 0.f;
    }
    __syncthreads();
    int r = threadIdx.x >> 5, c = threadIdx.x & 31;
    int row = row0 + r;
    if (row >= NNODES) return;
    float acc = b1[c];
    #pragma unroll
    for (int k = 0; k < 128; ++k) acc += fs[r][k] * w1s[c][k];
    h[row * 32 + c] = fmaxf(acc, 0.f);
}

// rnorm[row] = 1/max(||h[row,:]||, eps)
__global__ __launch_bounds__(256) void k_rnorm(
    const float* __restrict__ h, float* __restrict__ rnorm)
{
    int row = blockIdx.x * 256 + threadIdx.x;
    if (row >= NNODES) return;
    const float4* hp = reinterpret_cast<const float4*>(h + (size_t)row * 32);
    float ss = 0.f;
    #pragma unroll
    for (int i = 0; i < 8; ++i) {
        float4 t = hp[i];
        ss += t.x * t.x + t.y * t.y + t.z * t.z + t.w * t.w;
    }
    rnorm[row] = 1.f / fmaxf(sqrtf(ss), EPS);
}

// deg[d]++ per edge (int atomics only)
__global__ __launch_bounds__(256) void k_hist(
    const int* __restrict__ dst, int* __restrict__ deg)
{
    int k = blockIdx.x * 256 + threadIdx.x;
    if (k < NEDGES) atomicAdd(&deg[dst[k]], 1);
}

// single-block exclusive scan: deg[N] -> rowptr[N+1]; deg becomes the
// scatter cursor (overwritten with the row start offsets)
__global__ __launch_bounds__(1024) void k_scan(
    int* __restrict__ deg, int* __restrict__ rowptr)
{
    __shared__ int ls[1024];
    int t = threadIdx.x;
    const int CH = (NNODES + 1023) / 1024;   // 98
    int base = t * CH;
    int s = 0;
    for (int i = 0; i < CH; ++i) {
        int idx = base + i;
        if (idx < NNODES) s += deg[idx];
    }
    ls[t] = s;
    __syncthreads();
    for (int off = 1; off < 1024; off <<= 1) {
        int v = (t >= off) ? ls[t - off] : 0;
        __syncthreads();
        ls[t] += v;
        __syncthreads();
    }
    int run = (t == 0) ? 0 : ls[t - 1];
    for (int i = 0; i < CH; ++i) {
        int idx = base + i;
        if (idx < NNODES) {
            int d = deg[idx];
            rowptr[idx] = run;
            deg[idx] = run;      // cursor for k_scatter
            run += d;
        }
    }
    if (t == 1023) rowptr[NNODES] = run;   // == NEDGES
}

// esrc[pos] = src[k], grouped by dst
__global__ __launch_bounds__(256) void k_scatter(
    const int* __restrict__ src, const int* __restrict__ dst,
    int* __restrict__ cur, int* __restrict__ esrc)
{
    int k = blockIdx.x * 256 + threadIdx.x;
    if (k >= NEDGES) return;
    int pos = atomicAdd(&cur[dst[k]], 1);
    esrc[pos] = src[k];
}

// One wave per destination node. 4 edge-groups of 16 lanes; lane c2 of a
// group owns dims (2*c2, 2*c2+1) as float2. Online softmax in registers,
// flash-merge the 4 groups, write relu(acc/den).
__global__ __launch_bounds__(256) void k_agnn(
    const float* __restrict__ h, const float* __restrict__ rnorm,
    const int* __restrict__ rowptr, const int* __restrict__ esrc,
    const float* __restrict__ betas, int layer,
    float* __restrict__ hout)
{
    int node = blockIdx.x * 4 + (threadIdx.x >> 6);
    if (node >= NNODES) return;
    int lane = threadIdx.x & 63;
    int grp  = lane >> 4;
    int c2   = lane & 15;

    const float2* h2 = reinterpret_cast<const float2*>(h);
    float2 hd = h2[(size_t)node * 16 + c2];
    float rnd = rnorm[node] * betas[layer];

    int start = rowptr[node], end = rowptr[node + 1];
    float m = NEG, den = 0.f;
    float2 acc = make_float2(0.f, 0.f);

    for (int i = start + grp; i < end; i += 4) {
        int s = esrc[i];
        float2 hs = h2[(size_t)s * 16 + c2];
        float p = hs.x * hd.x + hs.y * hd.y;
        #pragma unroll
        for (int off = 8; off > 0; off >>= 1) p += __shfl_xor(p, off);
        float e = rnorm[s] * rnd * p;         // beta * cos(h_s, h_d)
        float mn = fmaxf(m, e);
        float sc = expf(m - mn);              // 0 on first edge (m = -1e30)
        float w  = expf(e - mn);
        den  = den * sc + w;
        acc.x = acc.x * sc + w * hs.x;
        acc.y = acc.y * sc + w * hs.y;
        m = mn;
    }

    // merge the 4 groups' online-softmax states (xor 16, then xor 32)
    #pragma unroll
    for (int D = 16; D <= 32; D <<= 1) {
        float m_o = __shfl_xor(m, D);
        float d_o = __shfl_xor(den, D);
        float ax  = __shfl_xor(acc.x, D);
        float ay  = __shfl_xor(acc.y, D);
        float mm = fmaxf(m, m_o);
        float sa = expf(m - mm), sb = expf(m_o - mm);
        den  = den * sa + d_o * sb;
        acc.x = acc.x * sa + ax * sb;
        acc.y = acc.y * sa + ay * sb;
        m = mm;
    }

    if (grp == 0) {
        float inv = 1.f / fmaxf(den, EPS);
        float2 o;
        o.x = fmaxf(acc.x * inv, 0.f);
        o.y = fmaxf(acc.y * inv, 0.f);
        reinterpret_cast<float2*>(hout)[(size_t)node * 16 + c2] = o;
    }
}

// out[N,64] = log_softmax(h @ w2[64,32]^T + b2)   (h already relu'd/divided)
__global__ __launch_bounds__(256) void k_final(
    const float* __restrict__ h, const float* __restrict__ w2,
    const float* __restrict__ b2, float* __restrict__ out)
{
    __shared__ float w2s[64][33];
    __shared__ float hs[4][32];
    for (int i = threadIdx.x; i < 64 * 32; i += 256)
        w2s[i >> 5][i & 31] = w2[i];
    int row0 = blockIdx.x * 4;
    if (threadIdx.x < 128) {
        int r = row0 + (threadIdx.x >> 5);
        int k = threadIdx.x & 31;
        hs[threadIdx.x >> 5][k] = (r < NNODES) ? h[r * 32 + k] : 0.f;
    }
    __syncthreads();
    int r = threadIdx.x >> 6, c = threadIdx.x & 63;
    int row = row0 + r;
    if (row >= NNODES) return;
    float acc = b2[c];
    #pragma unroll
    for (int k = 0; k < 32; ++k) acc += hs[r][k] * w2s[c][k];
    float mx = acc;
    #pragma unroll
    for (int off = 32; off > 0; off >>= 1)
        mx = fmaxf(mx, __shfl_xor(mx, off));
    float ex = expf(acc - mx);
    float sm = ex;
    #pragma unroll
    for (int off = 32; off > 0; off >>= 1)
        sm += __shfl_xor(sm, off);
    out[row * 64 + c] = acc - mx - logf(sm);
}

extern "C" void kernel_launch(void* const* d_in, const int* in_sizes, int n_in,
                              void* d_out, int out_size, void* d_ws, size_t ws_size,
                              hipStream_t stream)
{
    const float* feat  = (const float*)d_in[0];
    const int*   src   = (const int*)d_in[1];
    const int*   dst   = (const int*)d_in[2];
    const float* w1    = (const float*)d_in[3];
    const float* b1    = (const float*)d_in[4];
    const float* betas = (const float*)d_in[5];
    const float* w2    = (const float*)d_in[6];
    const float* b2    = (const float*)d_in[7];
    float* out = (float*)d_out;

    // workspace: hA[N*32] hB[N*32] rnorm[N] deg/cur[N] rowptr[N+1] esrc[E]
    // = 12.8 + 12.8 + 0.4 + 0.4 + 0.4 + 6.4 MB = 33.2 MB
    float* hA     = (float*)d_ws;
    float* hB     = hA + (size_t)NNODES * 32;
    float* rnorm  = hB + (size_t)NNODES * 32;
    int*   deg    = (int*)(rnorm + NNODES);
    int*   rowptr = deg + NNODES;
    int*   esrc   = rowptr + NNODES + 1;

    dim3 blk(256);
    int gNode = (NNODES + 255) / 256;
    int gEdge = (NEDGES + 255) / 256;
    int gWave = (NNODES + 3) / 4;

    // CSR build (identical for both layers — built once)
    hipMemsetAsync(deg, 0, (size_t)NNODES * 4, stream);
    k_hist<<<gEdge, blk, 0, stream>>>(dst, deg);
    k_scan<<<1, 1024, 0, stream>>>(deg, rowptr);
    k_scatter<<<gEdge, blk, 0, stream>>>(src, dst, deg, esrc);

    k_lin1<<<(NNODES + 7) / 8, blk, 0, stream>>>(feat, w1, b1, hA);

    k_rnorm<<<gNode, blk, 0, stream>>>(hA, rnorm);
    k_agnn<<<gWave, blk, 0, stream>>>(hA, rnorm, rowptr, esrc, betas, 0, hB);

    k_rnorm<<<gNode, blk, 0, stream>>>(hB, rnorm);
    k_agnn<<<gWave, blk, 0, stream>>>(hB, rnorm, rowptr, esrc, betas, 1, hA);

    k_final<<<gWave, blk, 0, stream>>>(hA, w2, b2, out);
}

// Round 3
// 455.313 us; speedup vs baseline: 12.7028x; 1.5250x over previous
//
#include <hip/hip_runtime.h>

#define NNODES 100000
#define NEDGES 1600000

#define SCAN_BS   256
#define SCAN_CH   4                       // nodes per thread
#define SCAN_TILE (SCAN_BS * SCAN_CH)     // 1024 nodes per block
#define NSCANB    ((NNODES + SCAN_TILE - 1) / SCAN_TILE)   // 98

static constexpr float EPS = 1e-12f;
static constexpr float NEG = -1e30f;   // finite "-inf": avoids NaN in empty-group merges

// h[N,32] = relu(feat[N,128] @ w1[32,128]^T + b1)
__global__ __launch_bounds__(256) void k_lin1(
    const float* __restrict__ feat, const float* __restrict__ w1,
    const float* __restrict__ b1, float* __restrict__ h)
{
    __shared__ float w1s[32][129];
    __shared__ float fs[8][128];
    for (int i = threadIdx.x; i < 32 * 128; i += 256)
        w1s[i >> 7][i & 127] = w1[i];
    int row0 = blockIdx.x * 8;
    for (int i = threadIdx.x; i < 8 * 128; i += 256) {
        int r = row0 + (i >> 7);
        fs[i >> 7][i & 127] = (r < NNODES) ? feat[r * 128 + (i & 127)] : 0.f;
    }
    __syncthreads();
    int r = threadIdx.x >> 5, c = threadIdx.x & 31;
    int row = row0 + r;
    if (row >= NNODES) return;
    float acc = b1[c];
    #pragma unroll
    for (int k = 0; k < 128; ++k) acc += fs[r][k] * w1s[c][k];
    h[row * 32 + c] = fmaxf(acc, 0.f);
}

// rnorm[row] = 1/max(||h[row,:]||, eps)
__global__ __launch_bounds__(256) void k_rnorm(
    const float* __restrict__ h, float* __restrict__ rnorm)
{
    int row = blockIdx.x * 256 + threadIdx.x;
    if (row >= NNODES) return;
    const float4* hp = reinterpret_cast<const float4*>(h + (size_t)row * 32);
    float ss = 0.f;
    #pragma unroll
    for (int i = 0; i < 8; ++i) {
        float4 t = hp[i];
        ss += t.x * t.x + t.y * t.y + t.z * t.z + t.w * t.w;
    }
    rnorm[row] = 1.f / fmaxf(sqrtf(ss), EPS);
}

// deg[d]++ per edge (int atomics only)
__global__ __launch_bounds__(256) void k_hist(
    const int* __restrict__ dst, int* __restrict__ deg)
{
    int k = blockIdx.x * 256 + threadIdx.x;
    if (k < NEDGES) atomicAdd(&deg[dst[k]], 1);
}

// --- hierarchical scan: deg[N] -> rowptr[N+1], deg becomes scatter cursor ---

// per-block sums
__global__ __launch_bounds__(SCAN_BS) void k_scanA(
    const int* __restrict__ deg, int* __restrict__ bsum)
{
    int t = threadIdx.x;
    int base = blockIdx.x * SCAN_TILE + t * SCAN_CH;
    int s = 0;
    #pragma unroll
    for (int i = 0; i < SCAN_CH; ++i) {
        int idx = base + i;
        if (idx < NNODES) s += deg[idx];
    }
    __shared__ int ls[SCAN_BS];
    ls[t] = s;
    __syncthreads();
    for (int off = SCAN_BS / 2; off > 0; off >>= 1) {
        if (t < off) ls[t] += ls[t + off];
        __syncthreads();
    }
    if (t == 0) bsum[blockIdx.x] = ls[0];
}

// one small block: exclusive scan of the NSCANB block sums
__global__ __launch_bounds__(128) void k_scanB(
    const int* __restrict__ bsum, int* __restrict__ boff,
    int* __restrict__ rowptr)
{
    int t = threadIdx.x;
    __shared__ int ls[128];
    ls[t] = (t < NSCANB) ? bsum[t] : 0;
    __syncthreads();
    for (int off = 1; off < 128; off <<= 1) {
        int u = (t >= off) ? ls[t - off] : 0;
        __syncthreads();
        ls[t] += u;
        __syncthreads();
    }
    if (t < NSCANB) boff[t] = (t == 0) ? 0 : ls[t - 1];
    if (t == 0) rowptr[NNODES] = NEDGES;   // total degree is known a priori
}

// block-local exclusive scan + block offset -> rowptr + cursor
__global__ __launch_bounds__(SCAN_BS) void k_scanC(
    int* __restrict__ deg, const int* __restrict__ boff,
    int* __restrict__ rowptr)
{
    int t = threadIdx.x;
    int base = blockIdx.x * SCAN_TILE + t * SCAN_CH;
    int vals[SCAN_CH];
    int s = 0;
    #pragma unroll
    for (int i = 0; i < SCAN_CH; ++i) {
        int idx = base + i;
        vals[i] = (idx < NNODES) ? deg[idx] : 0;
        s += vals[i];
    }
    __shared__ int ls[SCAN_BS];
    ls[t] = s;
    __syncthreads();
    for (int off = 1; off < SCAN_BS; off <<= 1) {
        int u = (t >= off) ? ls[t - off] : 0;
        __syncthreads();
        ls[t] += u;
        __syncthreads();
    }
    int run = boff[blockIdx.x] + ((t == 0) ? 0 : ls[t - 1]);
    #pragma unroll
    for (int i = 0; i < SCAN_CH; ++i) {
        int idx = base + i;
        if (idx < NNODES) {
            rowptr[idx] = run;
            deg[idx] = run;      // cursor for k_scatter
            run += vals[i];
        }
    }
}

// esrc[pos] = src[k], grouped by dst
__global__ __launch_bounds__(256) void k_scatter(
    const int* __restrict__ src, const int* __restrict__ dst,
    int* __restrict__ cur, int* __restrict__ esrc)
{
    int k = blockIdx.x * 256 + threadIdx.x;
    if (k >= NEDGES) return;
    int pos = atomicAdd(&cur[dst[k]], 1);
    esrc[pos] = src[k];
}

// One wave per destination node. 4 edge-groups of 16 lanes; lane c2 of a
// group owns dims (2*c2, 2*c2+1) as float2. Online softmax in registers,
// flash-merge the 4 groups, write relu(acc/den).
__global__ __launch_bounds__(256) void k_agnn(
    const float* __restrict__ h, const float* __restrict__ rnorm,
    const int* __restrict__ rowptr, const int* __restrict__ esrc,
    const float* __restrict__ betas, int layer,
    float* __restrict__ hout)
{
    int node = blockIdx.x * 4 + (threadIdx.x >> 6);
    if (node >= NNODES) return;
    int lane = threadIdx.x & 63;
    int grp  = lane >> 4;
    int c2   = lane & 15;

    const float2* h2 = reinterpret_cast<const float2*>(h);
    float2 hd = h2[(size_t)node * 16 + c2];
    float rnd = rnorm[node] * betas[layer];

    int start = rowptr[node], end = rowptr[node + 1];
    float m = NEG, den = 0.f;
    float2 acc = make_float2(0.f, 0.f);

    for (int i = start + grp; i < end; i += 4) {
        int s = esrc[i];
        float2 hs = h2[(size_t)s * 16 + c2];
        float p = hs.x * hd.x + hs.y * hd.y;
        #pragma unroll
        for (int off = 8; off > 0; off >>= 1) p += __shfl_xor(p, off);
        float e = rnorm[s] * rnd * p;         // beta * cos(h_s, h_d)
        float mn = fmaxf(m, e);
        float sc = expf(m - mn);              // 0 on first edge (m = -1e30)
        float w  = expf(e - mn);
        den  = den * sc + w;
        acc.x = acc.x * sc + w * hs.x;
        acc.y = acc.y * sc + w * hs.y;
        m = mn;
    }

    // merge the 4 groups' online-softmax states (xor 16, then xor 32)
    #pragma unroll
    for (int D = 16; D <= 32; D <<= 1) {
        float m_o = __shfl_xor(m, D);
        float d_o = __shfl_xor(den, D);
        float ax  = __shfl_xor(acc.x, D);
        float ay  = __shfl_xor(acc.y, D);
        float mm = fmaxf(m, m_o);
        float sa = expf(m - mm), sb = expf(m_o - mm);
        den  = den * sa + d_o * sb;
        acc.x = acc.x * sa + ax * sb;
        acc.y = acc.y * sa + ay * sb;
        m = mm;
    }

    if (grp == 0) {
        float inv = 1.f / fmaxf(den, EPS);
        float2 o;
        o.x = fmaxf(acc.x * inv, 0.f);
        o.y = fmaxf(acc.y * inv, 0.f);
        reinterpret_cast<float2*>(hout)[(size_t)node * 16 + c2] = o;
    }
}

// out[N,64] = log_softmax(h @ w2[64,32]^T + b2)   (h already relu'd/divided)
__global__ __launch_bounds__(256) void k_final(
    const float* __restrict__ h, const float* __restrict__ w2,
    const float* __restrict__ b2, float* __restrict__ out)
{
    __shared__ float w2s[64][33];
    __shared__ float hs[4][32];
    for (int i = threadIdx.x; i < 64 * 32; i += 256)
        w2s[i >> 5][i & 31] = w2[i];
    int row0 = blockIdx.x * 4;
    if (threadIdx.x < 128) {
        int r = row0 + (threadIdx.x >> 5);
        int k = threadIdx.x & 31;
        hs[threadIdx.x >> 5][k] = (r < NNODES) ? h[r * 32 + k] : 0.f;
    }
    __syncthreads();
    int r = threadIdx.x >> 6, c = threadIdx.x & 63;
    int row = row0 + r;
    if (row >= NNODES) return;
    float acc = b2[c];
    #pragma unroll
    for (int k = 0; k < 32; ++k) acc += hs[r][k] * w2s[c][k];
    float mx = acc;
    #pragma unroll
    for (int off = 32; off > 0; off >>= 1)
        mx = fmaxf(mx, __shfl_xor(mx, off));
    float ex = expf(acc - mx);
    float sm = ex;
    #pragma unroll
    for (int off = 32; off > 0; off >>= 1)
        sm += __shfl_xor(sm, off);
    out[row * 64 + c] = acc - mx - logf(sm);
}

extern "C" void kernel_launch(void* const* d_in, const int* in_sizes, int n_in,
                              void* d_out, int out_size, void* d_ws, size_t ws_size,
                              hipStream_t stream)
{
    const float* feat  = (const float*)d_in[0];
    const int*   src   = (const int*)d_in[1];
    const int*   dst   = (const int*)d_in[2];
    const float* w1    = (const float*)d_in[3];
    const float* b1    = (const float*)d_in[4];
    const float* betas = (const float*)d_in[5];
    const float* w2    = (const float*)d_in[6];
    const float* b2    = (const float*)d_in[7];
    float* out = (float*)d_out;

    // workspace: hA[N*32] hB[N*32] rnorm[N] deg/cur[N] rowptr[N+1] esrc[E]
    // bsum[NSCANB] boff[NSCANB]  => ~33.2 MB
    float* hA     = (float*)d_ws;
    float* hB     = hA + (size_t)NNODES * 32;
    float* rnorm  = hB + (size_t)NNODES * 32;
    int*   deg    = (int*)(rnorm + NNODES);
    int*   rowptr = deg + NNODES;
    int*   esrc   = rowptr + NNODES + 1;
    int*   bsum   = esrc + NEDGES;
    int*   boff   = bsum + NSCANB;

    dim3 blk(256);
    int gNode = (NNODES + 255) / 256;
    int gEdge = (NEDGES + 255) / 256;
    int gWave = (NNODES + 3) / 4;

    // CSR build (identical for both layers — built once)
    hipMemsetAsync(deg, 0, (size_t)NNODES * 4, stream);
    k_hist<<<gEdge, blk, 0, stream>>>(dst, deg);
    k_scanA<<<NSCANB, SCAN_BS, 0, stream>>>(deg, bsum);
    k_scanB<<<1, 128, 0, stream>>>(bsum, boff, rowptr);
    k_scanC<<<NSCANB, SCAN_BS, 0, stream>>>(deg, boff, rowptr);
    k_scatter<<<gEdge, blk, 0, stream>>>(src, dst, deg, esrc);

    k_lin1<<<(NNODES + 7) / 8, blk, 0, stream>>>(feat, w1, b1, hA);

    k_rnorm<<<gNode, blk, 0, stream>>>(hA, rnorm);
    k_agnn<<<gWave, blk, 0, stream>>>(hA, rnorm, rowptr, esrc, betas, 0, hB);

    k_rnorm<<<gNode, blk, 0, stream>>>(hB, rnorm);
    k_agnn<<<gWave, blk, 0, stream>>>(hB, rnorm, rowptr, esrc, betas, 1, hA);

    k_final<<<gWave, blk, 0, stream>>>(hA, w2, b2, out);
}

// Round 4
// 312.441 us; speedup vs baseline: 18.5116x; 1.4573x over previous
//
#include <hip/hip_runtime.h>

#define NNODES 100000
#define NEDGES 1600000

#define NBUCK  ((NNODES + 511) >> 9)      // 196 buckets of 512 nodes
#define BIN_EPT  16
#define BIN_TILE (256 * BIN_EPT)          // 4096 edges per bin block
#define NBINBLK  ((NEDGES + BIN_TILE - 1) / BIN_TILE)   // 391

static constexpr float EPS = 1e-12f;
static constexpr float NEG = -1e30f;   // finite "-inf": avoids NaN in empty merges

// ---------------- CSR build: bucketed counting sort ----------------

// coarse histogram over 196 buckets (LDS first, then one global add per bucket)
__global__ __launch_bounds__(256) void k_bhist(
    const int* __restrict__ dst, int* __restrict__ bcnt)
{
    __shared__ int cnt[NBUCK];
    for (int i = threadIdx.x; i < NBUCK; i += 256) cnt[i] = 0;
    __syncthreads();
    int base = blockIdx.x * BIN_TILE;
    #pragma unroll
    for (int i = 0; i < BIN_EPT; ++i) {
        int k = base + i * 256 + threadIdx.x;
        if (k < NEDGES) atomicAdd(&cnt[dst[k] >> 9], 1);
    }
    __syncthreads();
    for (int i = threadIdx.x; i < NBUCK; i += 256)
        if (cnt[i]) atomicAdd(&bcnt[i], cnt[i]);
}

// one small block: exclusive scan of bucket counts -> bbase, bcur
__global__ __launch_bounds__(256) void k_bscan(
    const int* __restrict__ bcnt, int* __restrict__ bbase,
    int* __restrict__ bcur, int* __restrict__ rowptr)
{
    __shared__ int ls[256];
    int t = threadIdx.x;
    ls[t] = (t < NBUCK) ? bcnt[t] : 0;
    __syncthreads();
    for (int off = 1; off < 256; off <<= 1) {
        int u = (t >= off) ? ls[t - off] : 0;
        __syncthreads();
        ls[t] += u;
        __syncthreads();
    }
    if (t < NBUCK) {
        int b = (t == 0) ? 0 : ls[t - 1];
        bbase[t] = b;
        bcur[t]  = b;
    }
    if (t == 0) rowptr[NNODES] = NEDGES;
}

// bin edges into bucket-contiguous packed[] : (dst&511)<<17 | src
__global__ __launch_bounds__(256) void k_bin(
    const int* __restrict__ src, const int* __restrict__ dst,
    int* __restrict__ bcur, unsigned* __restrict__ packed)
{
    __shared__ int cnt[NBUCK];
    __shared__ int gb[NBUCK];
    for (int i = threadIdx.x; i < NBUCK; i += 256) cnt[i] = 0;
    __syncthreads();
    unsigned pk[BIN_EPT];
    int bk[BIN_EPT];
    int base = blockIdx.x * BIN_TILE;
    #pragma unroll
    for (int i = 0; i < BIN_EPT; ++i) {
        int k = base + i * 256 + threadIdx.x;
        bk[i] = -1;
        if (k < NEDGES) {
            int d = dst[k], s = src[k];
            bk[i] = d >> 9;
            pk[i] = ((unsigned)(d & 511) << 17) | (unsigned)s;
            atomicAdd(&cnt[bk[i]], 1);
        }
    }
    __syncthreads();
    for (int i = threadIdx.x; i < NBUCK; i += 256) {
        int c = cnt[i];
        gb[i] = c ? atomicAdd(&bcur[i], c) : 0;
        cnt[i] = 0;
    }
    __syncthreads();
    #pragma unroll
    for (int i = 0; i < BIN_EPT; ++i) {
        if (bk[i] >= 0) {
            int pos = gb[bk[i]] + atomicAdd(&cnt[bk[i]], 1);
            packed[pos] = pk[i];
        }
    }
}

// one block per bucket: local count -> local scan -> rowptr + esrc scatter
// (esrc writes land in a ~33KB cache-resident window)
__global__ __launch_bounds__(512) void k_bucket(
    const unsigned* __restrict__ packed, const int* __restrict__ bbase,
    const int* __restrict__ bcnt, int* __restrict__ rowptr,
    int* __restrict__ esrc)
{
    __shared__ int cnt[512];
    __shared__ int loc[512];
    int b = blockIdx.x, t = threadIdx.x;
    int base = bbase[b];
    int n = bcnt[b];
    cnt[t] = 0;
    __syncthreads();
    for (int i = t; i < n; i += 512)
        atomicAdd(&cnt[packed[base + i] >> 17], 1);
    __syncthreads();
    int v = cnt[t];
    loc[t] = v;
    __syncthreads();
    for (int off = 1; off < 512; off <<= 1) {
        int u = (t >= off) ? loc[t - off] : 0;
        __syncthreads();
        loc[t] += u;
        __syncthreads();
    }
    int excl = loc[t] - v;
    int node = b * 512 + t;
    if (node < NNODES) rowptr[node] = base + excl;
    cnt[t] = base + excl;          // reuse as absolute cursor
    __syncthreads();
    for (int i = t; i < n; i += 512) {
        unsigned p = packed[base + i];
        int pos = atomicAdd(&cnt[p >> 17], 1);
        esrc[pos] = (int)(p & 0x1FFFFu);
    }
}

// ---------------- compute kernels ----------------

// h[N,32] = relu(feat @ w1^T + b1), fused rnorm. Grid-stride, 8 rows/tile.
__global__ __launch_bounds__(256) void k_lin1(
    const float* __restrict__ feat, const float* __restrict__ w1,
    const float* __restrict__ b1, float* __restrict__ h,
    float* __restrict__ rnorm)
{
    __shared__ float w1s[32][129];
    __shared__ float fs[8][128];
    for (int i = threadIdx.x; i < 32 * 128; i += 256)
        w1s[i >> 7][i & 127] = w1[i];
    int r = threadIdx.x >> 5, c = threadIdx.x & 31;
    float bc = b1[c];
    const int ntiles = (NNODES + 7) / 8;
    for (int tile = blockIdx.x; tile < ntiles; tile += gridDim.x) {
        int row0 = tile * 8;
        __syncthreads();   // w1s ready (1st iter) / fs free (later iters)
        for (int i = threadIdx.x; i < 8 * 128; i += 256) {
            int rr = row0 + (i >> 7);
            fs[i >> 7][i & 127] = (rr < NNODES) ? feat[rr * 128 + (i & 127)] : 0.f;
        }
        __syncthreads();
        int row = row0 + r;
        float acc = bc;
        #pragma unroll
        for (int k = 0; k < 128; ++k) acc += fs[r][k] * w1s[c][k];
        acc = fmaxf(acc, 0.f);
        float ss = acc * acc;
        #pragma unroll
        for (int off = 16; off > 0; off >>= 1) ss += __shfl_xor(ss, off);
        if (row < NNODES) {
            h[row * 32 + c] = acc;
            if (c == 0) rnorm[row] = 1.f / fmaxf(sqrtf(ss), EPS);
        }
    }
}

// One wave per destination node; 4 edge-groups of 16 lanes; online softmax.
// Optionally writes rnorm of the output row (for the next layer).
__global__ __launch_bounds__(256) void k_agnn(
    const float* __restrict__ h, const float* __restrict__ rnorm,
    const int* __restrict__ rowptr, const int* __restrict__ esrc,
    const float* __restrict__ betas, int layer,
    float* __restrict__ hout, float* __restrict__ rnout)
{
    int node = blockIdx.x * 4 + (threadIdx.x >> 6);
    if (node >= NNODES) return;
    int lane = threadIdx.x & 63;
    int grp  = lane >> 4;
    int c2   = lane & 15;

    const float2* h2 = reinterpret_cast<const float2*>(h);
    float2 hd = h2[(size_t)node * 16 + c2];
    float rnd = rnorm[node] * betas[layer];
    hd.x *= rnd; hd.y *= rnd;            // fold beta*rnorm_d into hd

    int start = rowptr[node], end = rowptr[node + 1];
    float m = NEG, den = 0.f;
    float2 acc = make_float2(0.f, 0.f);

    for (int i = start + grp; i < end; i += 4) {
        int s = esrc[i];
        float2 hs = h2[(size_t)s * 16 + c2];
        float p = hs.x * hd.x + hs.y * hd.y;
        #pragma unroll
        for (int off = 8; off > 0; off >>= 1) p += __shfl_xor(p, off);
        float e = rnorm[s] * p;              // beta * cos(h_s, h_d)
        float mn = fmaxf(m, e);
        float sc = expf(m - mn);
        float w  = expf(e - mn);
        den  = den * sc + w;
        acc.x = acc.x * sc + w * hs.x;
        acc.y = acc.y * sc + w * hs.y;
        m = mn;
    }

    #pragma unroll
    for (int D = 16; D <= 32; D <<= 1) {
        float m_o = __shfl_xor(m, D);
        float d_o = __shfl_xor(den, D);
        float ax  = __shfl_xor(acc.x, D);
        float ay  = __shfl_xor(acc.y, D);
        float mm = fmaxf(m, m_o);
        float sa = expf(m - mm), sb = expf(m_o - mm);
        den  = den * sa + d_o * sb;
        acc.x = acc.x * sa + ax * sb;
        acc.y = acc.y * sa + ay * sb;
        m = mm;
    }

    if (grp == 0) {
        float inv = 1.f / fmaxf(den, EPS);
        float2 o;
        o.x = fmaxf(acc.x * inv, 0.f);
        o.y = fmaxf(acc.y * inv, 0.f);
        reinterpret_cast<float2*>(hout)[(size_t)node * 16 + c2] = o;
        if (rnout) {
            float ss = o.x * o.x + o.y * o.y;
            #pragma unroll
            for (int off = 8; off > 0; off >>= 1) ss += __shfl_xor(ss, off);
            if (c2 == 0) rnout[node] = 1.f / fmaxf(sqrtf(ss), EPS);
        }
    }
}

// out[N,64] = log_softmax(h @ w2^T + b2). Grid-stride, 4 rows/tile.
__global__ __launch_bounds__(256) void k_final(
    const float* __restrict__ h, const float* __restrict__ w2,
    const float* __restrict__ b2, float* __restrict__ out)
{
    __shared__ float w2s[64][33];
    __shared__ float hs[4][32];
    for (int i = threadIdx.x; i < 64 * 32; i += 256)
        w2s[i >> 5][i & 31] = w2[i];
    int r = threadIdx.x >> 6, c = threadIdx.x & 63;
    float bc = b2[c];
    const int ntiles = (NNODES + 3) / 4;
    for (int tile = blockIdx.x; tile < ntiles; tile += gridDim.x) {
        int row0 = tile * 4;
        __syncthreads();
        if (threadIdx.x < 128) {
            int rr = row0 + (threadIdx.x >> 5);
            int k = threadIdx.x & 31;
            hs[threadIdx.x >> 5][k] = (rr < NNODES) ? h[rr * 32 + k] : 0.f;
        }
        __syncthreads();
        int row = row0 + r;
        float acc = bc;
        #pragma unroll
        for (int k = 0; k < 32; ++k) acc += hs[r][k] * w2s[c][k];
        float mx = acc;
        #pragma unroll
        for (int off = 32; off > 0; off >>= 1)
            mx = fmaxf(mx, __shfl_xor(mx, off));
        float ex = expf(acc - mx);
        float sm = ex;
        #pragma unroll
        for (int off = 32; off > 0; off >>= 1)
            sm += __shfl_xor(sm, off);
        if (row < NNODES) out[row * 64 + c] = acc - mx - logf(sm);
    }
}

extern "C" void kernel_launch(void* const* d_in, const int* in_sizes, int n_in,
                              void* d_out, int out_size, void* d_ws, size_t ws_size,
                              hipStream_t stream)
{
    const float* feat  = (const float*)d_in[0];
    const int*   src   = (const int*)d_in[1];
    const int*   dst   = (const int*)d_in[2];
    const float* w1    = (const float*)d_in[3];
    const float* b1    = (const float*)d_in[4];
    const float* betas = (const float*)d_in[5];
    const float* w2    = (const float*)d_in[6];
    const float* b2    = (const float*)d_in[7];
    float* out = (float*)d_out;

    // workspace (~33.2 MB): hA[N*32] hB[N*32] rnA[N] rnB[N] rowptr[N+1]
    // esrc[E] bcnt/bbase/bcur[196].  packed[E] aliases hB (dead until agnn L0).
    float*    hA     = (float*)d_ws;
    float*    hB     = hA + (size_t)NNODES * 32;
    float*    rnA    = hB + (size_t)NNODES * 32;
    float*    rnB    = rnA + NNODES;
    int*      rowptr = (int*)(rnB + NNODES);
    int*      esrc   = rowptr + NNODES + 1;
    int*      bcnt   = esrc + NEDGES;
    int*      bbase  = bcnt + NBUCK;
    int*      bcur   = bbase + NBUCK;
    unsigned* packed = (unsigned*)hB;

    dim3 blk(256);

    // CSR build (bucketed counting sort; built once, used by both layers)
    hipMemsetAsync(bcnt, 0, NBUCK * sizeof(int), stream);
    k_bhist<<<NBINBLK, blk, 0, stream>>>(dst, bcnt);
    k_bscan<<<1, blk, 0, stream>>>(bcnt, bbase, bcur, rowptr);
    k_bin<<<NBINBLK, blk, 0, stream>>>(src, dst, bcur, packed);
    k_bucket<<<NBUCK, 512, 0, stream>>>(packed, bbase, bcnt, rowptr, esrc);

    k_lin1<<<2048, blk, 0, stream>>>(feat, w1, b1, hA, rnA);

    int gWave = (NNODES + 3) / 4;
    k_agnn<<<gWave, blk, 0, stream>>>(hA, rnA, rowptr, esrc, betas, 0, hB, rnB);
    k_agnn<<<gWave, blk, 0, stream>>>(hB, rnB, rowptr, esrc, betas, 1, hA, nullptr);

    k_final<<<2048, blk, 0, stream>>>(hA, w2, b2, out);
}

// Round 5
// 288.869 us; speedup vs baseline: 20.0222x; 1.0816x over previous
//
#include <hip/hip_runtime.h>

#define NNODES 100000
#define NEDGES 1600000

#define NBUCK  ((NNODES + 511) >> 9)      // 196 buckets of 512 nodes
#define BIN_EPT  16
#define BIN_TILE (256 * BIN_EPT)          // 4096 edges per bin block
#define NBINBLK  ((NEDGES + BIN_TILE - 1) / BIN_TILE)   // 391

static_assert(NNODES % 4 == 0, "fused kernel assumes exact node quads");

static constexpr float EPS = 1e-12f;

// ---------------- CSR build: bucketed counting sort ----------------

__global__ __launch_bounds__(256) void k_bhist(
    const int* __restrict__ dst, int* __restrict__ bcnt)
{
    __shared__ int cnt[NBUCK];
    for (int i = threadIdx.x; i < NBUCK; i += 256) cnt[i] = 0;
    __syncthreads();
    int base = blockIdx.x * BIN_TILE;
    #pragma unroll
    for (int i = 0; i < BIN_EPT; ++i) {
        int k = base + i * 256 + threadIdx.x;
        if (k < NEDGES) atomicAdd(&cnt[dst[k] >> 9], 1);
    }
    __syncthreads();
    for (int i = threadIdx.x; i < NBUCK; i += 256)
        if (cnt[i]) atomicAdd(&bcnt[i], cnt[i]);
}

__global__ __launch_bounds__(256) void k_bscan(
    const int* __restrict__ bcnt, int* __restrict__ bbase,
    int* __restrict__ bcur, int* __restrict__ rowptr)
{
    __shared__ int ls[256];
    int t = threadIdx.x;
    ls[t] = (t < NBUCK) ? bcnt[t] : 0;
    __syncthreads();
    for (int off = 1; off < 256; off <<= 1) {
        int u = (t >= off) ? ls[t - off] : 0;
        __syncthreads();
        ls[t] += u;
        __syncthreads();
    }
    if (t < NBUCK) {
        int b = (t == 0) ? 0 : ls[t - 1];
        bbase[t] = b;
        bcur[t]  = b;
    }
    if (t == 0) rowptr[NNODES] = NEDGES;
}

// bin edges into bucket-contiguous packed[] : (dst&511)<<17 | src
__global__ __launch_bounds__(256) void k_bin(
    const int* __restrict__ src, const int* __restrict__ dst,
    int* __restrict__ bcur, unsigned* __restrict__ packed)
{
    __shared__ int cnt[NBUCK];
    __shared__ int gb[NBUCK];
    for (int i = threadIdx.x; i < NBUCK; i += 256) cnt[i] = 0;
    __syncthreads();
    unsigned pk[BIN_EPT];
    int bk[BIN_EPT];
    int base = blockIdx.x * BIN_TILE;
    #pragma unroll
    for (int i = 0; i < BIN_EPT; ++i) {
        int k = base + i * 256 + threadIdx.x;
        bk[i] = -1;
        if (k < NEDGES) {
            int d = dst[k], s = src[k];
            bk[i] = d >> 9;
            pk[i] = ((unsigned)(d & 511) << 17) | (unsigned)s;
            atomicAdd(&cnt[bk[i]], 1);
        }
    }
    __syncthreads();
    for (int i = threadIdx.x; i < NBUCK; i += 256) {
        int c = cnt[i];
        gb[i] = c ? atomicAdd(&bcur[i], c) : 0;
        cnt[i] = 0;
    }
    __syncthreads();
    #pragma unroll
    for (int i = 0; i < BIN_EPT; ++i) {
        if (bk[i] >= 0) {
            int pos = gb[bk[i]] + atomicAdd(&cnt[bk[i]], 1);
            packed[pos] = pk[i];
        }
    }
}

// one block per bucket: local count -> local scan -> rowptr + esrc scatter
__global__ __launch_bounds__(512) void k_bucket(
    const unsigned* __restrict__ packed, const int* __restrict__ bbase,
    const int* __restrict__ bcnt, int* __restrict__ rowptr,
    int* __restrict__ esrc)
{
    __shared__ int cnt[512];
    __shared__ int loc[512];
    int b = blockIdx.x, t = threadIdx.x;
    int base = bbase[b];
    int n = bcnt[b];
    cnt[t] = 0;
    __syncthreads();
    for (int i = t; i < n; i += 512)
        atomicAdd(&cnt[packed[base + i] >> 17], 1);
    __syncthreads();
    int v = cnt[t];
    loc[t] = v;
    __syncthreads();
    for (int off = 1; off < 512; off <<= 1) {
        int u = (t >= off) ? loc[t - off] : 0;
        __syncthreads();
        loc[t] += u;
        __syncthreads();
    }
    int excl = loc[t] - v;
    int node = b * 512 + t;
    if (node < NNODES) rowptr[node] = base + excl;
    cnt[t] = base + excl;          // absolute cursor
    __syncthreads();
    for (int i = t; i < n; i += 512) {
        unsigned p = packed[base + i];
        int pos = atomicAdd(&cnt[p >> 17], 1);
        esrc[pos] = (int)(p & 0x1FFFFu);
    }
}

// ---------------- compute kernels ----------------

// h[N,32] = relu(feat @ w1^T + b1), fused rnorm. Grid-stride, 8 rows/tile.
__global__ __launch_bounds__(256) void k_lin1(
    const float* __restrict__ feat, const float* __restrict__ w1,
    const float* __restrict__ b1, float* __restrict__ h,
    float* __restrict__ rnorm)
{
    __shared__ float w1s[32][129];
    __shared__ float fs[8][128];
    for (int i = threadIdx.x; i < 32 * 128; i += 256)
        w1s[i >> 7][i & 127] = w1[i];
    int r = threadIdx.x >> 5, c = threadIdx.x & 31;
    float bc = b1[c];
    const int ntiles = (NNODES + 7) / 8;
    for (int tile = blockIdx.x; tile < ntiles; tile += gridDim.x) {
        int row0 = tile * 8;
        __syncthreads();
        for (int i = threadIdx.x; i < 8 * 128; i += 256) {
            int rr = row0 + (i >> 7);
            fs[i >> 7][i & 127] = (rr < NNODES) ? feat[rr * 128 + (i & 127)] : 0.f;
        }
        __syncthreads();
        int row = row0 + r;
        float acc = bc;
        #pragma unroll
        for (int k = 0; k < 128; ++k) acc += fs[r][k] * w1s[c][k];
        acc = fmaxf(acc, 0.f);
        float ss = acc * acc;
        #pragma unroll
        for (int off = 16; off > 0; off >>= 1) ss += __shfl_xor(ss, off);
        if (row < NNODES) {
            h[row * 32 + c] = acc;
            if (c == 0) rnorm[row] = 1.f / fmaxf(sqrtf(ss), EPS);
        }
    }
}

// One wave per destination node; 4 edge-groups of 16 lanes.
// Constant-shift softmax: e = beta*cos in [-|beta|,|beta|], so
// w = exp(e - |beta|) needs no running max (shift cancels in alpha).
// FUSED=false: write relu(acc/den) row + its rnorm.
// FUSED=true : feed the row through W2/b2 + log_softmax, write out[N,64].
template <bool FUSED>
__global__ __launch_bounds__(256) void k_agnn(
    const float* __restrict__ h, const float* __restrict__ rnorm,
    const int* __restrict__ rowptr, const int* __restrict__ esrc,
    const float* __restrict__ betas, int layer,
    float* __restrict__ hout, float* __restrict__ rnout,
    const float* __restrict__ w2, const float* __restrict__ b2,
    float* __restrict__ out)
{
    __shared__ float w2s[64][33];     // only used when FUSED
    __shared__ float2 osm[4][16];
    if (FUSED) {
        for (int i = threadIdx.x; i < 64 * 32; i += 256)
            w2s[i >> 5][i & 31] = w2[i];
    }
    int wid  = threadIdx.x >> 6;
    int node = blockIdx.x * 4 + wid;
    int lane = threadIdx.x & 63;
    int grp  = lane >> 4;
    int c2   = lane & 15;

    const float2* h2 = reinterpret_cast<const float2*>(h);
    float beta = betas[layer];
    float absb = fabsf(beta);
    float2 hd = h2[(size_t)node * 16 + c2];
    float rnd = rnorm[node] * beta;
    hd.x *= rnd; hd.y *= rnd;          // fold beta*rnorm_d into hd

    int start = rowptr[node], end = rowptr[node + 1];
    float den = 0.f;
    float2 acc = make_float2(0.f, 0.f);

    for (int i = start + grp; i < end; i += 4) {
        int s = esrc[i];
        float2 hs = h2[(size_t)s * 16 + c2];
        float p = hs.x * hd.x + hs.y * hd.y;
        #pragma unroll
        for (int off = 8; off > 0; off >>= 1) p += __shfl_xor(p, off);
        float w = __expf(fmaf(rnorm[s], p, -absb));   // exp(e - |beta|)
        den   += w;
        acc.x += w * hs.x;
        acc.y += w * hs.y;
    }

    #pragma unroll
    for (int D = 16; D <= 32; D <<= 1) {
        den   += __shfl_xor(den, D);
        acc.x += __shfl_xor(acc.x, D);
        acc.y += __shfl_xor(acc.y, D);
    }

    float inv = 1.f / fmaxf(den, EPS);
    float2 o;
    o.x = fmaxf(acc.x * inv, 0.f);
    o.y = fmaxf(acc.y * inv, 0.f);

    if (!FUSED) {
        if (grp == 0) {
            reinterpret_cast<float2*>(hout)[(size_t)node * 16 + c2] = o;
            float ss = o.x * o.x + o.y * o.y;
            #pragma unroll
            for (int off = 8; off > 0; off >>= 1) ss += __shfl_xor(ss, off);
            if (c2 == 0) rnout[node] = 1.f / fmaxf(sqrtf(ss), EPS);
        }
    } else {
        if (grp == 0) osm[wid][c2] = o;
        __syncthreads();   // exact grid: no early returns, all threads arrive
        const float* op = reinterpret_cast<const float*>(osm[wid]);
        float a2 = b2[lane];
        #pragma unroll
        for (int k = 0; k < 32; ++k) a2 += op[k] * w2s[lane][k];
        float mx = a2;
        #pragma unroll
        for (int off = 32; off > 0; off >>= 1)
            mx = fmaxf(mx, __shfl_xor(mx, off));
        float ex = __expf(a2 - mx);
        float sm = ex;
        #pragma unroll
        for (int off = 32; off > 0; off >>= 1)
            sm += __shfl_xor(sm, off);
        out[(size_t)node * 64 + lane] = a2 - mx - __logf(sm);
    }
}

extern "C" void kernel_launch(void* const* d_in, const int* in_sizes, int n_in,
                              void* d_out, int out_size, void* d_ws, size_t ws_size,
                              hipStream_t stream)
{
    const float* feat  = (const float*)d_in[0];
    const int*   src   = (const int*)d_in[1];
    const int*   dst   = (const int*)d_in[2];
    const float* w1    = (const float*)d_in[3];
    const float* b1    = (const float*)d_in[4];
    const float* betas = (const float*)d_in[5];
    const float* w2    = (const float*)d_in[6];
    const float* b2    = (const float*)d_in[7];
    float* out = (float*)d_out;

    // workspace (~33.2 MB): hA[N*32] hB[N*32] rnA[N] rnB[N] rowptr[N+1]
    // esrc[E] bcnt/bbase/bcur[196].  packed[E] aliases hB (dead until agnn L0).
    float*    hA     = (float*)d_ws;
    float*    hB     = hA + (size_t)NNODES * 32;
    float*    rnA    = hB + (size_t)NNODES * 32;
    float*    rnB    = rnA + NNODES;
    int*      rowptr = (int*)(rnB + NNODES);
    int*      esrc   = rowptr + NNODES + 1;
    int*      bcnt   = esrc + NEDGES;
    int*      bbase  = bcnt + NBUCK;
    int*      bcur   = bbase + NBUCK;
    unsigned* packed = (unsigned*)hB;

    dim3 blk(256);

    // CSR build (built once, used by both layers)
    hipMemsetAsync(bcnt, 0, NBUCK * sizeof(int), stream);
    k_bhist<<<NBINBLK, blk, 0, stream>>>(dst, bcnt);
    k_bscan<<<1, blk, 0, stream>>>(bcnt, bbase, bcur, rowptr);
    k_bin<<<NBINBLK, blk, 0, stream>>>(src, dst, bcur, packed);
    k_bucket<<<NBUCK, 512, 0, stream>>>(packed, bbase, bcnt, rowptr, esrc);

    k_lin1<<<2048, blk, 0, stream>>>(feat, w1, b1, hA, rnA);

    int gWave = NNODES / 4;   // exact
    k_agnn<false><<<gWave, blk, 0, stream>>>(hA, rnA, rowptr, esrc, betas, 0,
                                             hB, rnB, nullptr, nullptr, nullptr);
    k_agnn<true><<<gWave, blk, 0, stream>>>(hB, rnB, rowptr, esrc, betas, 1,
                                            nullptr, nullptr, w2, b2, out);
}

// Round 6
// 243.289 us; speedup vs baseline: 23.7733x; 1.1873x over previous
//
#include <hip/hip_runtime.h>

#define NNODES 100000
#define NEDGES 1600000

#define NBUCK  ((NNODES + 511) >> 9)      // 196 buckets of 512 nodes
#define BIN_EPT  16
#define BIN_TILE (256 * BIN_EPT)          // 4096 edges per bin block
#define NBINBLK  ((NEDGES + BIN_TILE - 1) / BIN_TILE)   // 391

static_assert(NNODES % 4 == 0, "fused kernel assumes exact node quads");

static constexpr float EPS = 1e-12f;

// ---------------- CSR build: bucketed counting sort ----------------

__global__ __launch_bounds__(256) void k_bhist(
    const int* __restrict__ dst, int* __restrict__ bcnt)
{
    __shared__ int cnt[NBUCK];
    for (int i = threadIdx.x; i < NBUCK; i += 256) cnt[i] = 0;
    __syncthreads();
    int base = blockIdx.x * BIN_TILE;
    #pragma unroll
    for (int i = 0; i < BIN_EPT; ++i) {
        int k = base + i * 256 + threadIdx.x;
        if (k < NEDGES) atomicAdd(&cnt[dst[k] >> 9], 1);
    }
    __syncthreads();
    for (int i = threadIdx.x; i < NBUCK; i += 256)
        if (cnt[i]) atomicAdd(&bcnt[i], cnt[i]);
}

__global__ __launch_bounds__(256) void k_bscan(
    const int* __restrict__ bcnt, int* __restrict__ bbase,
    int* __restrict__ bcur, int* __restrict__ rowptr)
{
    __shared__ int ls[256];
    int t = threadIdx.x;
    ls[t] = (t < NBUCK) ? bcnt[t] : 0;
    __syncthreads();
    for (int off = 1; off < 256; off <<= 1) {
        int u = (t >= off) ? ls[t - off] : 0;
        __syncthreads();
        ls[t] += u;
        __syncthreads();
    }
    if (t < NBUCK) {
        int b = (t == 0) ? 0 : ls[t - 1];
        bbase[t] = b;
        bcur[t]  = b;
    }
    if (t == 0) rowptr[NNODES] = NEDGES;
}

// bin edges into bucket-contiguous packed[] : (dst&511)<<17 | src
__global__ __launch_bounds__(256) void k_bin(
    const int* __restrict__ src, const int* __restrict__ dst,
    int* __restrict__ bcur, unsigned* __restrict__ packed)
{
    __shared__ int cnt[NBUCK];
    __shared__ int gb[NBUCK];
    for (int i = threadIdx.x; i < NBUCK; i += 256) cnt[i] = 0;
    __syncthreads();
    unsigned pk[BIN_EPT];
    int bk[BIN_EPT];
    int base = blockIdx.x * BIN_TILE;
    #pragma unroll
    for (int i = 0; i < BIN_EPT; ++i) {
        int k = base + i * 256 + threadIdx.x;
        bk[i] = -1;
        if (k < NEDGES) {
            int d = dst[k], s = src[k];
            bk[i] = d >> 9;
            pk[i] = ((unsigned)(d & 511) << 17) | (unsigned)s;
            atomicAdd(&cnt[bk[i]], 1);
        }
    }
    __syncthreads();
    for (int i = threadIdx.x; i < NBUCK; i += 256) {
        int c = cnt[i];
        gb[i] = c ? atomicAdd(&bcur[i], c) : 0;
        cnt[i] = 0;
    }
    __syncthreads();
    #pragma unroll
    for (int i = 0; i < BIN_EPT; ++i) {
        if (bk[i] >= 0) {
            int pos = gb[bk[i]] + atomicAdd(&cnt[bk[i]], 1);
            packed[pos] = pk[i];
        }
    }
}

// one block per bucket: local count -> local scan -> rowptr + esrc scatter
__global__ __launch_bounds__(512) void k_bucket(
    const unsigned* __restrict__ packed, const int* __restrict__ bbase,
    const int* __restrict__ bcnt, int* __restrict__ rowptr,
    int* __restrict__ esrc)
{
    __shared__ int cnt[512];
    __shared__ int loc[512];
    int b = blockIdx.x, t = threadIdx.x;
    int base = bbase[b];
    int n = bcnt[b];
    cnt[t] = 0;
    __syncthreads();
    for (int i = t; i < n; i += 512)
        atomicAdd(&cnt[packed[base + i] >> 17], 1);
    __syncthreads();
    int v = cnt[t];
    loc[t] = v;
    __syncthreads();
    for (int off = 1; off < 512; off <<= 1) {
        int u = (t >= off) ? loc[t - off] : 0;
        __syncthreads();
        loc[t] += u;
        __syncthreads();
    }
    int excl = loc[t] - v;
    int node = b * 512 + t;
    if (node < NNODES) rowptr[node] = base + excl;
    cnt[t] = base + excl;          // absolute cursor
    __syncthreads();
    for (int i = t; i < n; i += 512) {
        unsigned p = packed[base + i];
        int pos = atomicAdd(&cnt[p >> 17], 1);
        esrc[pos] = (int)(p & 0x1FFFFu);
    }
}

// ---------------- compute kernels ----------------

// h[N,32] = relu(feat @ w1^T + b1), fused rnorm. Grid-stride, 8 rows/tile.
__global__ __launch_bounds__(256) void k_lin1(
    const float* __restrict__ feat, const float* __restrict__ w1,
    const float* __restrict__ b1, float* __restrict__ h,
    float* __restrict__ rnorm)
{
    __shared__ float w1s[32][129];
    __shared__ float fs[8][128];
    for (int i = threadIdx.x; i < 32 * 128; i += 256)
        w1s[i >> 7][i & 127] = w1[i];
    int r = threadIdx.x >> 5, c = threadIdx.x & 31;
    float bc = b1[c];
    const int ntiles = (NNODES + 7) / 8;
    for (int tile = blockIdx.x; tile < ntiles; tile += gridDim.x) {
        int row0 = tile * 8;
        __syncthreads();
        for (int i = threadIdx.x; i < 8 * 128; i += 256) {
            int rr = row0 + (i >> 7);
            fs[i >> 7][i & 127] = (rr < NNODES) ? feat[rr * 128 + (i & 127)] : 0.f;
        }
        __syncthreads();
        int row = row0 + r;
        float acc = bc;
        #pragma unroll
        for (int k = 0; k < 128; ++k) acc += fs[r][k] * w1s[c][k];
        acc = fmaxf(acc, 0.f);
        float ss = acc * acc;
        #pragma unroll
        for (int off = 16; off > 0; off >>= 1) ss += __shfl_xor(ss, off);
        if (row < NNODES) {
            h[row * 32 + c] = acc;
            if (c == 0) rnorm[row] = 1.f / fmaxf(sqrtf(ss), EPS);
        }
    }
}

// One wave per destination node; 8 groups of 8 lanes (float4 per lane),
// 2-edge manual unroll => 16 independent gather chains per wave.
// Constant-shift softmax: e in [-|beta|,|beta|] => w = exp(e-|beta|), no max.
template <bool FUSED>
__global__ __launch_bounds__(256) void k_agnn(
    const float* __restrict__ h, const float* __restrict__ rnorm,
    const int* __restrict__ rowptr, const int* __restrict__ esrc,
    const float* __restrict__ betas, int layer,
    float* __restrict__ hout, float* __restrict__ rnout,
    const float* __restrict__ w2, const float* __restrict__ b2,
    float* __restrict__ out)
{
    __shared__ float w2s[64][33];     // only used when FUSED
    __shared__ float4 osm[4][8];
    if (FUSED) {
        for (int i = threadIdx.x; i < 64 * 32; i += 256)
            w2s[i >> 5][i & 31] = w2[i];
    }
    int wid  = threadIdx.x >> 6;
    int node = blockIdx.x * 4 + wid;
    int lane = threadIdx.x & 63;
    int grp  = lane >> 3;            // 8 edge-groups
    int c4   = lane & 7;             // float4 slot within the 32-dim row

    const float4* h4 = reinterpret_cast<const float4*>(h);
    float beta = betas[layer];
    float absb = fabsf(beta);
    float4 hd = h4[(size_t)node * 8 + c4];
    float rnd = rnorm[node] * beta;
    hd.x *= rnd; hd.y *= rnd; hd.z *= rnd; hd.w *= rnd;

    int start = rowptr[node], end = rowptr[node + 1];
    float den = 0.f;
    float4 acc = make_float4(0.f, 0.f, 0.f, 0.f);

    for (int i0 = start + grp; i0 < end; i0 += 16) {
        int i1 = i0 + 8;
        bool has1 = (i1 < end);
        int s0 = esrc[i0];
        int s1 = has1 ? esrc[i1] : s0;
        float4 a0 = h4[(size_t)s0 * 8 + c4];
        float4 a1 = h4[(size_t)s1 * 8 + c4];
        float rn0 = rnorm[s0];
        float rn1 = rnorm[s1];
        float p0 = a0.x * hd.x + a0.y * hd.y + a0.z * hd.z + a0.w * hd.w;
        float p1 = a1.x * hd.x + a1.y * hd.y + a1.z * hd.z + a1.w * hd.w;
        #pragma unroll
        for (int off = 4; off > 0; off >>= 1) {
            p0 += __shfl_xor(p0, off);
            p1 += __shfl_xor(p1, off);
        }
        float w0 = __expf(fmaf(rn0, p0, -absb));
        float w1 = has1 ? __expf(fmaf(rn1, p1, -absb)) : 0.f;
        den += w0 + w1;
        acc.x += w0 * a0.x + w1 * a1.x;
        acc.y += w0 * a0.y + w1 * a1.y;
        acc.z += w0 * a0.z + w1 * a1.z;
        acc.w += w0 * a0.w + w1 * a1.w;
    }

    // merge the 8 groups (xor 8, 16, 32)
    #pragma unroll
    for (int D = 8; D <= 32; D <<= 1) {
        den   += __shfl_xor(den, D);
        acc.x += __shfl_xor(acc.x, D);
        acc.y += __shfl_xor(acc.y, D);
        acc.z += __shfl_xor(acc.z, D);
        acc.w += __shfl_xor(acc.w, D);
    }

    float inv = 1.f / fmaxf(den, EPS);
    float4 o;
    o.x = fmaxf(acc.x * inv, 0.f);
    o.y = fmaxf(acc.y * inv, 0.f);
    o.z = fmaxf(acc.z * inv, 0.f);
    o.w = fmaxf(acc.w * inv, 0.f);

    if (!FUSED) {
        if (grp == 0) {
            reinterpret_cast<float4*>(hout)[(size_t)node * 8 + c4] = o;
            float ss = o.x * o.x + o.y * o.y + o.z * o.z + o.w * o.w;
            #pragma unroll
            for (int off = 4; off > 0; off >>= 1) ss += __shfl_xor(ss, off);
            if (c4 == 0) rnout[node] = 1.f / fmaxf(sqrtf(ss), EPS);
        }
    } else {
        if (grp == 0) osm[wid][c4] = o;
        __syncthreads();   // exact grid: all threads arrive
        const float* op = reinterpret_cast<const float*>(osm[wid]);
        float a2 = b2[lane];
        #pragma unroll
        for (int k = 0; k < 32; ++k) a2 += op[k] * w2s[lane][k];
        float mx = a2;
        #pragma unroll
        for (int off = 32; off > 0; off >>= 1)
            mx = fmaxf(mx, __shfl_xor(mx, off));
        float ex = __expf(a2 - mx);
        float sm = ex;
        #pragma unroll
        for (int off = 32; off > 0; off >>= 1)
            sm += __shfl_xor(sm, off);
        out[(size_t)node * 64 + lane] = a2 - mx - __logf(sm);
    }
}

extern "C" void kernel_launch(void* const* d_in, const int* in_sizes, int n_in,
                              void* d_out, int out_size, void* d_ws, size_t ws_size,
                              hipStream_t stream)
{
    const float* feat  = (const float*)d_in[0];
    const int*   src   = (const int*)d_in[1];
    const int*   dst   = (const int*)d_in[2];
    const float* w1    = (const float*)d_in[3];
    const float* b1    = (const float*)d_in[4];
    const float* betas = (const float*)d_in[5];
    const float* w2    = (const float*)d_in[6];
    const float* b2    = (const float*)d_in[7];
    float* out = (float*)d_out;

    // workspace (~33.2 MB): hA[N*32] hB[N*32] rnA[N] rnB[N] rowptr[N+1]
    // esrc[E] bcnt/bbase/bcur[196].  packed[E] aliases hB (dead until agnn L0).
    float*    hA     = (float*)d_ws;
    float*    hB     = hA + (size_t)NNODES * 32;
    float*    rnA    = hB + (size_t)NNODES * 32;
    float*    rnB    = rnA + NNODES;
    int*      rowptr = (int*)(rnB + NNODES);
    int*      esrc   = rowptr + NNODES + 1;
    int*      bcnt   = esrc + NEDGES;
    int*      bbase  = bcnt + NBUCK;
    int*      bcur   = bbase + NBUCK;
    unsigned* packed = (unsigned*)hB;

    dim3 blk(256);

    // CSR build (built once, used by both layers)
    hipMemsetAsync(bcnt, 0, NBUCK * sizeof(int), stream);
    k_bhist<<<NBINBLK, blk, 0, stream>>>(dst, bcnt);
    k_bscan<<<1, blk, 0, stream>>>(bcnt, bbase, bcur, rowptr);
    k_bin<<<NBINBLK, blk, 0, stream>>>(src, dst, bcur, packed);
    k_bucket<<<NBUCK, 512, 0, stream>>>(packed, bbase, bcnt, rowptr, esrc);

    k_lin1<<<2048, blk, 0, stream>>>(feat, w1, b1, hA, rnA);

    int gWave = NNODES / 4;   // exact
    k_agnn<false><<<gWave, blk, 0, stream>>>(hA, rnA, rowptr, esrc, betas, 0,
                                             hB, rnB, nullptr, nullptr, nullptr);
    k_agnn<true><<<gWave, blk, 0, stream>>>(hB, rnB, rowptr, esrc, betas, 1,
                                            nullptr, nullptr, w2, b2, out);
}